// Round 2
// baseline (141.429 us; speedup 1.0000x reference)
//
#include <hip/hip_runtime.h>
#include <hip/hip_bf16.h>

typedef __bf16 bf16x8 __attribute__((ext_vector_type(8)));
typedef float  f32x4  __attribute__((ext_vector_type(4)));

#define VOCAB 24
#define EDIM  16
#define HDIM  32
#define TLEN  128
#define GSTR  22   // gbuf row stride in f32 (88 B): 8B-aligned pairs, ~2-way banks max

__device__ __forceinline__ float fast_sig(float x) {
    // sigmoid(x) = 1 / (1 + 2^(-x*log2(e)))
    float t = __builtin_amdgcn_exp2f(x * -1.44269504f);
    return __builtin_amdgcn_rcpf(1.0f + t);
}
__device__ __forceinline__ float fast_tanh(float x) {
    // tanh(x) = 2/(1+2^(-2x*log2(e))) - 1
    float t = __builtin_amdgcn_exp2f(x * -2.88539008f);
    return __builtin_amdgcn_rcpf(1.0f + t) * 2.0f - 1.0f;
}

// Block = 4 waves, 16 batch rows. Wave w computes gate quadrant w
// (columns [32w,32w+32) of gates[16][128]) via 2x2 MFMA 16x16x32, gates go
// through LDS, then wave w applies the LSTM pointwise update for rows
// [4w,4w+4) (2 elements per lane, c-state in registers), writes bf16 h for
// the next step's shared A-fragment. 2 barriers/step.
__global__ __launch_bounds__(256, 4) void lstm_fused(
    const int*   __restrict__ x,     // [B][128]
    const float* __restrict__ emb,   // [24][16]
    const float* __restrict__ W_ih,  // [128][16]
    const float* __restrict__ W_hh,  // [128][32]
    const float* __restrict__ b_ih,  // [128]
    const float* __restrict__ b_hh,  // [128]
    const float* __restrict__ fc_w,  // [2][32]
    const float* __restrict__ fc_b,  // [2]
    float*       __restrict__ out)   // [B][2]
{
    __shared__ __align__(16) float  gbuf[128][GSTR];  // gates [gate][row], f32
    __shared__ __align__(16) __bf16 hbuf[2][16][40];  // h double-buffer, 80B rows
    __shared__ __align__(16) float  fbuf[16][33];     // final h (f32) for FC

    const int tid   = threadIdx.x;
    const int wid   = tid >> 6;          // 0..3 : gate quadrant / row group
    const int lane  = tid & 63;
    const int l15   = lane & 15;
    const int hi    = lane >> 4;         // 0..3
    const int kbase = hi * 8;
    const int row0  = blockIdx.x * 16;

    // ---- startup: B-fragments for this wave's two gate tiles ----
    // B-frag: n = l15 (+16*tile), k = kbase + i
    bf16x8 b1f[2];  // W_hh^T : B1[k=j][g] = W_hh[g][j]
    bf16x8 b2f[2];  // table  : B2[k=v][g] = emb[v].W_ih[g] + b_ih[g]+b_hh[g]
    #pragma unroll
    for (int q = 0; q < 2; ++q) {
        const int g = (2 * wid + q) * 16 + l15;
        const float* wrow = W_hh + g * HDIM;
        #pragma unroll
        for (int i = 0; i < 8; ++i)
            b1f[q][i] = (__bf16)wrow[kbase + i];
        const float bias = b_ih[g] + b_hh[g];
        const float* wi = W_ih + g * EDIM;
        #pragma unroll
        for (int i = 0; i < 8; ++i) {
            const int v = kbase + i;
            float s = 0.0f;
            if (v < VOCAB) {
                s = bias;
                #pragma unroll
                for (int e = 0; e < EDIM; ++e)
                    s += emb[v * EDIM + e] * wi[e];
            }
            b2f[q][i] = (__bf16)s;
        }
    }

    // update-phase lane mapping: element (row, j) ownership, constant over t
    const int uj = lane >> 1;                    // hidden/gate col j: 0..31
    const int ur = 4 * wid + 2 * (lane & 1);     // rows ur, ur+1
    float c0 = 0.0f, c1 = 0.0f;

    const int* xrow = x + (row0 + l15) * TLEN;   // A-row of this lane = l15

    int4 xq;
    for (int t = 0; t < TLEN; ++t) {
        if ((t & 3) == 0) xq = *(const int4*)(xrow + t);
        const int xv = (t & 1) ? ((t & 2) ? xq.w : xq.y)
                               : ((t & 2) ? xq.z : xq.x);

        // one-hot A2: A2[row=l15][k] = (k == x[row][t])
        bf16x8 a2;
        #pragma unroll
        for (int i = 0; i < 8; ++i)
            a2[i] = (kbase + i == xv) ? (__bf16)1.0f : (__bf16)0.0f;

        bf16x8 a1;
        if (t > 0)   // uniform branch; hbuf[(t-1)&1] ready since barrier B of t-1
            a1 = *(const bf16x8*)&hbuf[(t - 1) & 1][l15][kbase];

        const f32x4 z = {0.f, 0.f, 0.f, 0.f};
        f32x4 acc0 = __builtin_amdgcn_mfma_f32_16x16x32_bf16(a2, b2f[0], z, 0, 0, 0);
        f32x4 acc1 = __builtin_amdgcn_mfma_f32_16x16x32_bf16(a2, b2f[1], z, 0, 0, 0);
        if (t > 0) {
            acc0 = __builtin_amdgcn_mfma_f32_16x16x32_bf16(a1, b1f[0], acc0, 0, 0, 0);
            acc1 = __builtin_amdgcn_mfma_f32_16x16x32_bf16(a1, b1f[1], acc1, 0, 0, 0);
        }

        // scatter gates to LDS: acc reg r = row 4*hi+r, col = tile*16 + l15
        {
            const int g0 = 2 * wid * 16 + l15;
            float2 w01, w23;
            w01.x = acc0[0]; w01.y = acc0[1]; w23.x = acc0[2]; w23.y = acc0[3];
            *(float2*)&gbuf[g0][4 * hi]     = w01;
            *(float2*)&gbuf[g0][4 * hi + 2] = w23;
            w01.x = acc1[0]; w01.y = acc1[1]; w23.x = acc1[2]; w23.y = acc1[3];
            *(float2*)&gbuf[g0 + 16][4 * hi]     = w01;
            *(float2*)&gbuf[g0 + 16][4 * hi + 2] = w23;
        }
        __syncthreads();   // A: gates visible

        // gather i,f,g,o for (ur,uj),(ur+1,uj)
        const float2 gi = *(const float2*)&gbuf[uj     ][ur];
        const float2 gf = *(const float2*)&gbuf[32 + uj][ur];
        const float2 gg = *(const float2*)&gbuf[64 + uj][ur];
        const float2 go = *(const float2*)&gbuf[96 + uj][ur];

        const float i0 = fast_sig(gi.x), f0 = fast_sig(gf.x);
        const float G0 = fast_tanh(gg.x), o0 = fast_sig(go.x);
        c0 = f0 * c0 + i0 * G0;
        const float h0 = o0 * fast_tanh(c0);

        const float i1 = fast_sig(gi.y), f1 = fast_sig(gf.y);
        const float G1 = fast_tanh(gg.y), o1 = fast_sig(go.y);
        c1 = f1 * c1 + i1 * G1;
        const float h1 = o1 * fast_tanh(c1);

        hbuf[t & 1][ur    ][uj] = (__bf16)h0;
        hbuf[t & 1][ur + 1][uj] = (__bf16)h1;
        if (t == TLEN - 1) {
            fbuf[ur    ][uj] = h0;   // exact f32 for FC
            fbuf[ur + 1][uj] = h1;
        }
        __syncthreads();   // B: h ready; gbuf free for rewrite
    }

    // ---- FC epilogue: out[b] = h_last[b] @ fc_w^T + fc_b ----
    if (tid < 16) {
        float o0 = fc_b[0], o1 = fc_b[1];
        #pragma unroll
        for (int j = 0; j < HDIM; ++j) {
            const float h = fbuf[tid][j];
            o0 += fc_w[j]        * h;
            o1 += fc_w[HDIM + j] * h;
        }
        float2 res;
        res.x = o0; res.y = o1;
        *(float2*)&out[(row0 + tid) * 2] = res;
    }
}

extern "C" void kernel_launch(void* const* d_in, const int* in_sizes, int n_in,
                              void* d_out, int out_size, void* d_ws, size_t ws_size,
                              hipStream_t stream) {
    const int*   x    = (const int*)  d_in[0];
    const float* emb  = (const float*)d_in[1];
    const float* W_ih = (const float*)d_in[2];
    const float* W_hh = (const float*)d_in[3];
    const float* b_ih = (const float*)d_in[4];
    const float* b_hh = (const float*)d_in[5];
    const float* fc_w = (const float*)d_in[6];
    const float* fc_b = (const float*)d_in[7];
    float* out = (float*)d_out;

    const int B    = in_sizes[0] / TLEN;   // 16384
    const int nblk = B / 16;               // 1024 blocks x 4 waves = 16 waves/CU

    lstm_fused<<<nblk, 256, 0, stream>>>(x, emb, W_ih, W_hh, b_ih, b_hh, fc_w, fc_b, out);
}